// Round 9
// baseline (86.106 us; speedup 1.0000x reference)
//
#include <hip/hip_runtime.h>

// T=512, B=32 -> 16384 (t,b) pairs, D=128, 9 effective table rows.
// positions uniform 0..15 -> bucket 8 (p>=8) holds ~50% of pairs.
//
// R8 PROBE: identical kernel launched 3x (idempotent: pure function of
// unmodified inputs, overwrites same outputs). (dur_us - 70.4)/2 measures
// per-launch kernel cost + gap, separating kernel time from harness floor.
#define DEMB    128
#define LSTRIDE 130                // LDS staging row stride (bank-conflict pad)

using short8 = __attribute__((ext_vector_type(8))) short;
using f32x4  = __attribute__((ext_vector_type(4))) float;

// fp32 -> bf16 round-to-nearest-even
__device__ __forceinline__ unsigned short f2bf(float f) {
    unsigned u = __float_as_uint(f);
    u = u + 0x7FFFu + ((u >> 16) & 1u);
    return (unsigned short)(u >> 16);
}
__device__ __forceinline__ unsigned pack2(float a, float b) {
    return (unsigned)f2bf(a) | ((unsigned)f2bf(b) << 16);
}

// B-fragment LDS layout (verified R1-R8):
//   frag[nt*256 + ks*64 + lane] (uint4) holds
//   M[r][d = ks*32 + (lane>>4)*8 + j][e = nt*16 + (lane&15)], j=0..7
__global__ __launch_bounds__(256) void mpt_kernel(
    const int*   __restrict__ positions,
    const float* __restrict__ table,
    const float* __restrict__ x,
    float*       __restrict__ out) {

    __shared__ unsigned short sm[128 * LSTRIDE];  // 33.3 KB full-table staging
    __shared__ uint4 frag[2048];                  // 32 KB B-fragments for this r
    __shared__ int   sel[512];                    // matching pair indices
    __shared__ int   scnt;

    const int bid = blockIdx.x;
    const int tid = threadIdx.x;

    // ---- block -> (r, slice). r=8: 256 blocks x 64 pairs; r<8: 32 blocks x 512.
    int r, base, npos;
    if (bid < 256) { r = 8; base = bid * 64;  npos = 64;  }
    else { r = (bid - 256) >> 5; base = ((bid - 256) & 31) * 512; npos = 512; }

    if (tid == 0) scnt = 0;
    __syncthreads();          // fence scnt before atomics (placed BEFORE loads
                              // so the barrier's vmcnt drain costs nothing)

    // ---- 1) issue ALL table staging loads: 128 rows x 32 float4, 16/thread
    const float* Mr = table + r * DEMB * DEMB;
    float4 st[16];
#pragma unroll
    for (int f4 = 0; f4 < 16; ++f4) {
        const int id  = f4 * 256 + tid;     // 0..4095
        const int row = id >> 5;            // 0..127
        const int c4  = id & 31;            // float4 within row
        st[f4] = ((const float4*)(Mr + row * DEMB))[c4];
    }

    // ---- selection runs under the staging-load shadow (LDS atomic rank only)
    for (int i = tid; i < npos; i += 256) {
        const int p = positions[base + i];
        const bool hit = (r == 8) ? (p >= 8) : (p == r);
        if (hit) { const int k = atomicAdd(&scnt, 1); sel[k] = base + i; }
    }

    // ---- 2a) convert + store staging rows (packed dword writes, 2/float4)
#pragma unroll
    for (int f4 = 0; f4 < 16; ++f4) {
        const int id  = f4 * 256 + tid;
        const int row = id >> 5;
        const int c4  = id & 31;
        unsigned* dst = (unsigned*)&sm[row * LSTRIDE + c4 * 4];
        dst[0] = pack2(st[f4].x, st[f4].y);
        dst[1] = pack2(st[f4].z, st[f4].w);
    }
    __syncthreads();

    // ---- 2b) assemble all 2048 B-fragments, 8 per thread
#pragma unroll
    for (int f = 0; f < 8; ++f) {
        const int fid  = f * 256 + tid;     // 0..2047 = nt*256 + ks*64 + lane
        const int lane = fid & 63;
        const int ks   = (fid >> 6) & 3;
        const int nt   = fid >> 8;
        const int e    = nt * 16 + (lane & 15);
        const int d0   = ks * 32 + ((lane >> 4) << 3);
        union { unsigned short us[8]; uint4 v; } u;
#pragma unroll
        for (int j = 0; j < 8; ++j)
            u.us[j] = sm[(d0 + j) * LSTRIDE + e];
        frag[fid] = u.v;
    }
    __syncthreads();   // also fences sel/scnt for phase 3

    // ---- 3) MFMA tiles over this block's pairs (proven core, B from LDS).
    const int wave = tid >> 6;
    const int lane = tid & 63;
    const int m16  = lane & 15;     // m (pair-in-tile) for A; n (col) for C/D
    const int quad = lane >> 4;
    const int cnt  = scnt;

    for (int tb = wave * 16; tb < cnt; tb += 64) {
        const int nm = ((cnt - tb) < 16) ? (cnt - tb) : 16;  // 1..16

        // A fragments: A[m = lane&15][k = ks*32 + quad*8 + j]
        const int slotA = sel[tb + ((m16 < nm) ? m16 : 0)];
        const float* xrow = x + (size_t)slotA * DEMB;
        short8 a[4];
#pragma unroll
        for (int ks = 0; ks < 4; ++ks) {
            const float4* s4 = (const float4*)(xrow + ks * 32 + quad * 8);
            const float4 f0 = s4[0];
            const float4 f1 = s4[1];
            union { unsigned short us[8]; short8 s8; } ua;
            ua.us[0] = f2bf(f0.x); ua.us[1] = f2bf(f0.y);
            ua.us[2] = f2bf(f0.z); ua.us[3] = f2bf(f0.w);
            ua.us[4] = f2bf(f1.x); ua.us[5] = f2bf(f1.y);
            ua.us[6] = f2bf(f1.z); ua.us[7] = f2bf(f1.w);
            a[ks] = ua.s8;
        }

        // C/D rows: col = lane&15, row m = quad*4 + i (slots straight from LDS)
        int  prow[4];
        bool pval[4];
#pragma unroll
        for (int i = 0; i < 4; ++i) {
            const int m = quad * 4 + i;
            pval[i] = m < nm;
            prow[i] = sel[tb + (pval[i] ? m : 0)];
        }

#pragma unroll 2
        for (int nt = 0; nt < 8; ++nt) {
            f32x4 acc = {0.f, 0.f, 0.f, 0.f};
#pragma unroll
            for (int ks = 0; ks < 4; ++ks) {
                union { uint4 v4; short8 s8; } ub;
                ub.v4 = frag[(nt * 4 + ks) * 64 + lane];
                acc = __builtin_amdgcn_mfma_f32_16x16x32_bf16(a[ks], ub.s8, acc, 0, 0, 0);
            }
            const int col = nt * 16 + m16;
#pragma unroll
            for (int i = 0; i < 4; ++i)
                if (pval[i])
                    out[(size_t)prow[i] * DEMB + col] = acc[i];
        }
    }
}

extern "C" void kernel_launch(void* const* d_in, const int* in_sizes, int n_in,
                              void* d_out, int out_size, void* d_ws, size_t ws_size,
                              hipStream_t stream) {
    const int*   positions = (const int*)d_in[0];   // (16384,) int32
    const float* outputs   = (const float*)d_in[1]; // (16384, 128) fp32
    const float* table     = (const float*)d_in[2]; // (9, 128, 128) fp32
    float* out = (float*)d_out;                     // (16384, 128) fp32

    // PROBE: 3 identical launches (idempotent). (dur - single-launch)/2
    // = per-launch kernel cost incl. gap.
    hipLaunchKernelGGL(mpt_kernel, dim3(512), dim3(256), 0, stream,
                       positions, table, outputs, out);
    hipLaunchKernelGGL(mpt_kernel, dim3(512), dim3(256), 0, stream,
                       positions, table, outputs, out);
    hipLaunchKernelGGL(mpt_kernel, dim3(512), dim3(256), 0, stream,
                       positions, table, outputs, out);
}

// Round 11
// 71.311 us; speedup vs baseline: 1.2075x; 1.2075x over previous
//
#include <hip/hip_runtime.h>

// T=512, B=32 -> 16384 (t,b) pairs, D=128, 9 effective table rows.
// positions uniform 0..15 -> bucket 8 (p>=8) holds ~50% of pairs.
//
// Single-dispatch design (R6/R8-proven) + R9 phase-3 restructure:
//   - work unit = (tile, nt-half): all 4 waves active (was 2), 16 MFMA/unit
//   - first unit's x-loads issued BEFORE fragment assembly (sel valid after
//     barrier B) so HBM latency hides under the LDS gather.
#define DEMB    128
#define LSTRIDE 130                // LDS staging row stride (bank-conflict pad)

using short8 = __attribute__((ext_vector_type(8))) short;
using f32x4  = __attribute__((ext_vector_type(4))) float;

// fp32 -> bf16 round-to-nearest-even
__device__ __forceinline__ unsigned short f2bf(float f) {
    unsigned u = __float_as_uint(f);
    u = u + 0x7FFFu + ((u >> 16) & 1u);
    return (unsigned short)(u >> 16);
}
__device__ __forceinline__ unsigned pack2(float a, float b) {
    return (unsigned)f2bf(a) | ((unsigned)f2bf(b) << 16);
}

// B-fragment LDS layout (verified R1-R8):
//   frag[nt*256 + ks*64 + lane] (uint4) holds
//   M[r][d = ks*32 + (lane>>4)*8 + j][e = nt*16 + (lane&15)], j=0..7
__global__ __launch_bounds__(256) void mpt_kernel(
    const int*   __restrict__ positions,
    const float* __restrict__ table,
    const float* __restrict__ x,
    float*       __restrict__ out) {

    __shared__ unsigned short sm[128 * LSTRIDE];  // 33.3 KB full-table staging
    __shared__ uint4 frag[2048];                  // 32 KB B-fragments for this r
    __shared__ int   sel[512];                    // matching pair indices
    __shared__ int   scnt;

    const int bid = blockIdx.x;
    const int tid = threadIdx.x;

    // ---- block -> (r, slice). r=8: 256 blocks x 64 pairs; r<8: 32 blocks x 512.
    int r, base, npos;
    if (bid < 256) { r = 8; base = bid * 64;  npos = 64;  }
    else { r = (bid - 256) >> 5; base = ((bid - 256) & 31) * 512; npos = 512; }

    if (tid == 0) scnt = 0;
    __syncthreads();          // fence scnt before atomics (before loads: free)

    // ---- 1) issue ALL table staging loads: 128 rows x 32 float4, 16/thread
    const float* Mr = table + r * DEMB * DEMB;
    float4 st[16];
#pragma unroll
    for (int f4 = 0; f4 < 16; ++f4) {
        const int id  = f4 * 256 + tid;     // 0..4095
        const int row = id >> 5;            // 0..127
        const int c4  = id & 31;            // float4 within row
        st[f4] = ((const float4*)(Mr + row * DEMB))[c4];
    }

    // ---- selection runs under the staging-load shadow (LDS atomic rank only)
    for (int i = tid; i < npos; i += 256) {
        const int p = positions[base + i];
        const bool hit = (r == 8) ? (p >= 8) : (p == r);
        if (hit) { const int k = atomicAdd(&scnt, 1); sel[k] = base + i; }
    }

    // ---- 2a) convert + store staging rows (packed dword writes, 2/float4)
#pragma unroll
    for (int f4 = 0; f4 < 16; ++f4) {
        const int id  = f4 * 256 + tid;
        const int row = id >> 5;
        const int c4  = id & 31;
        unsigned* dst = (unsigned*)&sm[row * LSTRIDE + c4 * 4];
        dst[0] = pack2(st[f4].x, st[f4].y);
        dst[1] = pack2(st[f4].z, st[f4].w);
    }
    __syncthreads();   // barrier B: sm staged; sel/scnt also final past here

    const int wave = tid >> 6;
    const int lane = tid & 63;
    const int m16  = lane & 15;     // m (pair-in-tile) for A; n (col) for C/D
    const int quad = lane >> 4;
    const int cnt  = scnt;
    const int nu   = (((cnt + 15) >> 4) << 1);  // work units = tiles * 2

    // ---- 2p) peel unit `wave`: issue x-loads NOW so HBM latency hides
    //          under the fragment assembly below.
    float4 xf[8];
    int  prow[4];
    bool pval[4];
    bool have = (wave < nu);
    if (have) {
        const int tb = (wave >> 1) * 16;
        const int nm = ((cnt - tb) < 16) ? (cnt - tb) : 16;
        const int slotA = sel[tb + ((m16 < nm) ? m16 : 0)];
        const float* xrow = x + (size_t)slotA * DEMB;
#pragma unroll
        for (int ks = 0; ks < 4; ++ks) {
            const float4* s4 = (const float4*)(xrow + ks * 32 + quad * 8);
            xf[2 * ks]     = s4[0];
            xf[2 * ks + 1] = s4[1];
        }
#pragma unroll
        for (int i = 0; i < 4; ++i) {
            const int m = quad * 4 + i;
            pval[i] = m < nm;
            prow[i] = sel[tb + (pval[i] ? m : 0)];
        }
    }

    // ---- 2b) assemble all 2048 B-fragments, 8 per thread
#pragma unroll
    for (int f = 0; f < 8; ++f) {
        const int fid  = f * 256 + tid;     // 0..2047 = nt*256 + ks*64 + lane
        const int ln   = fid & 63;
        const int ks   = (fid >> 6) & 3;
        const int nt   = fid >> 8;
        const int e    = nt * 16 + (ln & 15);
        const int d0   = ks * 32 + ((ln >> 4) << 3);
        union { unsigned short us[8]; uint4 v; } u;
#pragma unroll
        for (int j = 0; j < 8; ++j)
            u.us[j] = sm[(d0 + j) * LSTRIDE + e];
        frag[fid] = u.v;
    }
    __syncthreads();   // barrier C: frag ready

    // ---- 3) MFMA units: unit u = (tile u>>1, nt-half u&1), all 4 waves.
    for (int u = wave; u < nu; u += 4) {
        const int tb  = (u >> 1) * 16;
        const int nt0 = (u & 1) << 2;       // nt base: 0 or 4
        const int nm  = ((cnt - tb) < 16) ? (cnt - tb) : 16;

        if (!have) {
            const int slotA = sel[tb + ((m16 < nm) ? m16 : 0)];
            const float* xrow = x + (size_t)slotA * DEMB;
#pragma unroll
            for (int ks = 0; ks < 4; ++ks) {
                const float4* s4 = (const float4*)(xrow + ks * 32 + quad * 8);
                xf[2 * ks]     = s4[0];
                xf[2 * ks + 1] = s4[1];
            }
#pragma unroll
            for (int i = 0; i < 4; ++i) {
                const int m = quad * 4 + i;
                pval[i] = m < nm;
                prow[i] = sel[tb + (pval[i] ? m : 0)];
            }
        }
        have = false;

        // A fragments: A[m = lane&15][k = ks*32 + quad*8 + j]
        short8 a[4];
#pragma unroll
        for (int ks = 0; ks < 4; ++ks) {
            const float4 f0 = xf[2 * ks];
            const float4 f1 = xf[2 * ks + 1];
            union { unsigned short us[8]; short8 s8; } ua;
            ua.us[0] = f2bf(f0.x); ua.us[1] = f2bf(f0.y);
            ua.us[2] = f2bf(f0.z); ua.us[3] = f2bf(f0.w);
            ua.us[4] = f2bf(f1.x); ua.us[5] = f2bf(f1.y);
            ua.us[6] = f2bf(f1.z); ua.us[7] = f2bf(f1.w);
            a[ks] = ua.s8;
        }

#pragma unroll
        for (int nt = 0; nt < 4; ++nt) {
            const int ntt = nt0 + nt;
            f32x4 acc = {0.f, 0.f, 0.f, 0.f};
#pragma unroll
            for (int ks = 0; ks < 4; ++ks) {
                union { uint4 v4; short8 s8; } ub;
                ub.v4 = frag[(ntt * 4 + ks) * 64 + lane];
                acc = __builtin_amdgcn_mfma_f32_16x16x32_bf16(a[ks], ub.s8, acc, 0, 0, 0);
            }
            const int col = ntt * 16 + m16;
#pragma unroll
            for (int i = 0; i < 4; ++i)
                if (pval[i])
                    out[(size_t)prow[i] * DEMB + col] = acc[i];
        }
    }
}

extern "C" void kernel_launch(void* const* d_in, const int* in_sizes, int n_in,
                              void* d_out, int out_size, void* d_ws, size_t ws_size,
                              hipStream_t stream) {
    const int*   positions = (const int*)d_in[0];   // (16384,) int32
    const float* outputs   = (const float*)d_in[1]; // (16384, 128) fp32
    const float* table     = (const float*)d_in[2]; // (9, 128, 128) fp32
    float* out = (float*)d_out;                     // (16384, 128) fp32

    hipLaunchKernelGGL(mpt_kernel, dim3(512), dim3(256), 0, stream,
                       positions, table, outputs, out);
}